// Round 1
// baseline (701.451 us; speedup 1.0000x reference)
//
#include <hip/hip_runtime.h>
#include <hip/hip_bf16.h>

#define BB 8
#define TT 32
#define NN 256
#define DD 256
#define HH 8
#define DH 32

// ---------------------------------------------------------------------------
// K1: TAtt[b,n,d] = sum_t x[b,t,n,d] * softmax_t(x[b,:,n,d])
// One thread per (b,n,d). Coalesced across d (innermost).
// ---------------------------------------------------------------------------
__global__ __launch_bounds__(256) void tatt_kernel(const float* __restrict__ x,
                                                   float* __restrict__ tatt) {
    int gid = blockIdx.x * 256 + threadIdx.x;      // over B*N*D = 524288
    int b = gid >> 16;                             // / (N*D)
    int rem = gid & 0xFFFF;                        // n*D + d
    const float* xp = x + (size_t)b * TT * NN * DD + rem;
    float vals[TT];
    float mx = -3.0e38f;
#pragma unroll
    for (int t = 0; t < TT; ++t) {
        vals[t] = xp[(size_t)t * (NN * DD)];
        mx = fmaxf(mx, vals[t]);
    }
    float se = 0.f, wsum = 0.f;
#pragma unroll
    for (int t = 0; t < TT; ++t) {
        float e = __expf(vals[t] - mx);
        se += e;
        wsum += e * vals[t];
    }
    tatt[gid] = wsum / se;
}

// ---------------------------------------------------------------------------
// K2: K[b,h,n,j] = dot(TAtt[b,n,:], W_K[h*32+j,:]);  V likewise.
// One block per (b,n). Thread c computes output column c for both K and V.
// ---------------------------------------------------------------------------
__global__ __launch_bounds__(256) void kv_kernel(const float* __restrict__ tatt,
                                                 const float* __restrict__ Wk,
                                                 const float* __restrict__ Wv,
                                                 float* __restrict__ Kp,
                                                 float* __restrict__ Vp) {
    __shared__ float trow[DD];
    int bid = blockIdx.x;       // b*N + n
    int b = bid >> 8;
    int n = bid & 255;
    int tid = threadIdx.x;      // 256 = output column
    trow[tid] = tatt[(size_t)bid * DD + tid];
    __syncthreads();
    const float4* wk4 = (const float4*)(Wk + (size_t)tid * DD);
    const float4* wv4 = (const float4*)(Wv + (size_t)tid * DD);
    const float4* t4 = (const float4*)trow;
    float accK = 0.f, accV = 0.f;
#pragma unroll 8
    for (int k = 0; k < DD / 4; ++k) {
        float4 tv = t4[k];
        float4 a = wk4[k];
        float4 v = wv4[k];
        accK += tv.x * a.x + tv.y * a.y + tv.z * a.z + tv.w * a.w;
        accV += tv.x * v.x + tv.y * v.y + tv.z * v.z + tv.w * v.w;
    }
    int h = tid >> 5, j = tid & 31;
    size_t o = (((size_t)b * HH + h) * NN + n) * DH + j;
    Kp[o] = accK;
    Vp[o] = accV;
}

// ---------------------------------------------------------------------------
// K3: Q = X @ W_Q^T   (X = x flattened [B*T*N, 256])
// 64x64 tile per block, k-chunks of 64, transposed LDS tiles, 4x4 reg tile.
// Output stored bf16 in layout [B][T][H][N][32].
// ---------------------------------------------------------------------------
__global__ __launch_bounds__(256) void qproj_kernel(const float* __restrict__ x,
                                                    const float* __restrict__ Wq,
                                                    __hip_bfloat16* __restrict__ Qp) {
    __shared__ float Xt[64][68];   // [k][row]   (68: 16B-aligned + conflict pad)
    __shared__ float Wt[64][68];   // [k][col]
    int bid = blockIdx.x;
    int ct = bid & 3;              // 4 col tiles
    int rt = bid >> 2;             // 1024 row tiles
    int row0 = rt * 64, col0 = ct * 64;
    int tid = threadIdx.x;
    int tx = tid & 15, ty = tid >> 4;
    float acc[4][4] = {};

    for (int kc = 0; kc < 4; ++kc) {
        int kk0 = kc * 64;
#pragma unroll
        for (int roff = 0; roff < 4; ++roff) {
            int r = roff * 16 + ty;
            float4 xv = *(const float4*)(x + (size_t)(row0 + r) * DD + kk0 + tx * 4);
            Xt[tx * 4 + 0][r] = xv.x;
            Xt[tx * 4 + 1][r] = xv.y;
            Xt[tx * 4 + 2][r] = xv.z;
            Xt[tx * 4 + 3][r] = xv.w;
            float4 wv = *(const float4*)(Wq + (size_t)(col0 + r) * DD + kk0 + tx * 4);
            Wt[tx * 4 + 0][r] = wv.x;
            Wt[tx * 4 + 1][r] = wv.y;
            Wt[tx * 4 + 2][r] = wv.z;
            Wt[tx * 4 + 3][r] = wv.w;
        }
        __syncthreads();
#pragma unroll 4
        for (int k = 0; k < 64; ++k) {
            float4 a = *(const float4*)&Xt[k][ty * 4];
            float4 w = *(const float4*)&Wt[k][tx * 4];
            acc[0][0] += a.x * w.x; acc[0][1] += a.x * w.y; acc[0][2] += a.x * w.z; acc[0][3] += a.x * w.w;
            acc[1][0] += a.y * w.x; acc[1][1] += a.y * w.y; acc[1][2] += a.y * w.z; acc[1][3] += a.y * w.w;
            acc[2][0] += a.z * w.x; acc[2][1] += a.z * w.y; acc[2][2] += a.z * w.z; acc[2][3] += a.z * w.w;
            acc[3][0] += a.w * w.x; acc[3][1] += a.w * w.y; acc[3][2] += a.w * w.z; acc[3][3] += a.w * w.w;
        }
        __syncthreads();
    }

#pragma unroll
    for (int i = 0; i < 4; ++i) {
        int row = row0 + ty * 4 + i;
        int b = row >> 13;             // / (T*N)
        int t = (row >> 8) & 31;
        int n = row & 255;
#pragma unroll
        for (int j = 0; j < 4; ++j) {
            int col = col0 + tx * 4 + j;
            int h = col >> 5, jj = col & 31;
            size_t o = ((((size_t)b * TT + t) * HH + h) * NN + n) * DH + jj;
            Qp[o] = __float2bfloat16(acc[i][j]);
        }
    }
}

// ---------------------------------------------------------------------------
// K4: per (b,t,h): S = Q_h K_h^T / sqrt(32); P = relu(S); O = P V_h + V_h
// One block per (b,t,h); 128 threads, each owns rows n and n+128.
// ---------------------------------------------------------------------------
__global__ __launch_bounds__(128) void attn_kernel(const __hip_bfloat16* __restrict__ Qp,
                                                   const float* __restrict__ Kp,
                                                   const float* __restrict__ Vp,
                                                   float* __restrict__ out) {
    __shared__ float Kl[NN][DH];   // 32 KB
    __shared__ float Vl[NN][DH];   // 32 KB
    int bid = blockIdx.x;          // b*T*H + t*H + h
    int h = bid & 7;
    int t = (bid >> 3) & 31;
    int b = bid >> 8;
    int tid = threadIdx.x;

    const float* kb = Kp + ((size_t)b * HH + h) * NN * DH;
    const float* vb = Vp + ((size_t)b * HH + h) * NN * DH;
#pragma unroll
    for (int i = 0; i < (NN * DH / 4) / 128; ++i) {
        int idx = i * 128 + tid;
        ((float4*)Kl)[idx] = ((const float4*)kb)[idx];
        ((float4*)Vl)[idx] = ((const float4*)vb)[idx];
    }
    __syncthreads();

    int n1 = tid, n2 = tid + 128;
    const __hip_bfloat16* q1p = Qp + ((((size_t)b * TT + t) * HH + h) * NN + n1) * DH;
    const __hip_bfloat16* q2p = q1p + (size_t)128 * DH;
    float4 q1[8], q2[8];
#pragma unroll
    for (int j4 = 0; j4 < 8; ++j4) {
        q1[j4].x = __bfloat162float(q1p[j4 * 4 + 0]);
        q1[j4].y = __bfloat162float(q1p[j4 * 4 + 1]);
        q1[j4].z = __bfloat162float(q1p[j4 * 4 + 2]);
        q1[j4].w = __bfloat162float(q1p[j4 * 4 + 3]);
        q2[j4].x = __bfloat162float(q2p[j4 * 4 + 0]);
        q2[j4].y = __bfloat162float(q2p[j4 * 4 + 1]);
        q2[j4].z = __bfloat162float(q2p[j4 * 4 + 2]);
        q2[j4].w = __bfloat162float(q2p[j4 * 4 + 3]);
    }
    float4 acc1[8], acc2[8];
#pragma unroll
    for (int j4 = 0; j4 < 8; ++j4) {
        acc1[j4] = make_float4(0.f, 0.f, 0.f, 0.f);
        acc2[j4] = make_float4(0.f, 0.f, 0.f, 0.f);
    }
    const float scale = 0.17677669529663688f;   // 1/sqrt(32)

    for (int m = 0; m < NN; ++m) {
        const float4* kr = (const float4*)Kl[m];
        float s1 = 0.f, s2 = 0.f;
#pragma unroll
        for (int j4 = 0; j4 < 8; ++j4) {
            float4 kv = kr[j4];
            s1 += q1[j4].x * kv.x + q1[j4].y * kv.y + q1[j4].z * kv.z + q1[j4].w * kv.w;
            s2 += q2[j4].x * kv.x + q2[j4].y * kv.y + q2[j4].z * kv.z + q2[j4].w * kv.w;
        }
        float p1 = fmaxf(s1 * scale, 0.f);
        float p2 = fmaxf(s2 * scale, 0.f);
        const float4* vr = (const float4*)Vl[m];
#pragma unroll
        for (int j4 = 0; j4 < 8; ++j4) {
            float4 vv = vr[j4];
            acc1[j4].x += p1 * vv.x; acc1[j4].y += p1 * vv.y; acc1[j4].z += p1 * vv.z; acc1[j4].w += p1 * vv.w;
            acc2[j4].x += p2 * vv.x; acc2[j4].y += p2 * vv.y; acc2[j4].z += p2 * vv.z; acc2[j4].w += p2 * vv.w;
        }
    }

    // epilogue: + identity (out += V[n]) and store
    float* o1 = out + (((size_t)b * TT + t) * NN + n1) * DD + h * DH;
    float* o2 = out + (((size_t)b * TT + t) * NN + n2) * DD + h * DH;
    const float4* v1r = (const float4*)Vl[n1];
    const float4* v2r = (const float4*)Vl[n2];
#pragma unroll
    for (int j4 = 0; j4 < 8; ++j4) {
        float4 vv = v1r[j4];
        float4 r;
        r.x = acc1[j4].x + vv.x; r.y = acc1[j4].y + vv.y;
        r.z = acc1[j4].z + vv.z; r.w = acc1[j4].w + vv.w;
        ((float4*)o1)[j4] = r;
        vv = v2r[j4];
        r.x = acc2[j4].x + vv.x; r.y = acc2[j4].y + vv.y;
        r.z = acc2[j4].z + vv.z; r.w = acc2[j4].w + vv.w;
        ((float4*)o2)[j4] = r;
    }
}

// ---------------------------------------------------------------------------
extern "C" void kernel_launch(void* const* d_in, const int* in_sizes, int n_in,
                              void* d_out, int out_size, void* d_ws, size_t ws_size,
                              hipStream_t stream) {
    (void)in_sizes; (void)n_in; (void)out_size; (void)ws_size;
    const float* x  = (const float*)d_in[0];
    // d_in[1] = boxes_in_flat: unused by the reference forward.
    const float* Wq = (const float*)d_in[2];
    const float* Wk = (const float*)d_in[3];
    const float* Wv = (const float*)d_in[4];
    float* out = (float*)d_out;

    // workspace layout (floats): TAtt[524288] | K[524288] | V[524288] | Q bf16[16777216]
    float* tatt = (float*)d_ws;
    float* Kp = tatt + (size_t)BB * NN * DD;
    float* Vp = Kp + (size_t)BB * HH * NN * DH;
    __hip_bfloat16* Qp = (__hip_bfloat16*)(Vp + (size_t)BB * HH * NN * DH);

    tatt_kernel<<<(BB * NN * DD) / 256, 256, 0, stream>>>(x, tatt);
    kv_kernel<<<BB * NN, 256, 0, stream>>>(tatt, Wk, Wv, Kp, Vp);
    qproj_kernel<<<(BB * TT * NN / 64) * (DD / 64), 256, 0, stream>>>(x, Wq, Qp);
    attn_kernel<<<BB * TT * HH, 128, 0, stream>>>(Qp, Kp, Vp, out);
}

// Round 2
// 360.763 us; speedup vs baseline: 1.9444x; 1.9444x over previous
//
#include <hip/hip_runtime.h>
#include <hip/hip_bf16.h>

#define BB 8
#define TT 32
#define NN 256
#define DD 256
#define HH 8
#define DH 32

typedef __attribute__((ext_vector_type(8))) short short8v;   // 8 bf16 = 4 VGPR
typedef __attribute__((ext_vector_type(4))) float f32x4;
typedef __attribute__((ext_vector_type(4))) unsigned int u32x4;

static __device__ __forceinline__ unsigned short f2bfu(float f) {
    __hip_bfloat16 h = __float2bfloat16(f);
    unsigned short u;
    __builtin_memcpy(&u, &h, 2);
    return u;
}
static __device__ __forceinline__ unsigned int pkbf(float a, float b) {
    float2 f2; f2.x = a; f2.y = b;
    __hip_bfloat162 h2 = __float22bfloat162_rn(f2);
    unsigned int u;
    __builtin_memcpy(&u, &h2, 4);
    return u;
}

// ---------------------------------------------------------------------------
// K1: TAtt[b,n,d] = sum_t x[b,t,n,d] * softmax_t(x[b,:,n,d])
// ---------------------------------------------------------------------------
__global__ __launch_bounds__(256) void tatt_kernel(const float* __restrict__ x,
                                                   float* __restrict__ tatt) {
    int gid = blockIdx.x * 256 + threadIdx.x;      // over B*N*D = 524288
    int b = gid >> 16;
    int rem = gid & 0xFFFF;
    const float* xp = x + (size_t)b * TT * NN * DD + rem;
    float vals[TT];
    float mx = -3.0e38f;
#pragma unroll
    for (int t = 0; t < TT; ++t) {
        vals[t] = xp[(size_t)t * (NN * DD)];
        mx = fmaxf(mx, vals[t]);
    }
    float se = 0.f, wsum = 0.f;
#pragma unroll
    for (int t = 0; t < TT; ++t) {
        float e = __expf(vals[t] - mx);
        se += e;
        wsum += e * vals[t];
    }
    tatt[gid] = wsum / se;
}

// ---------------------------------------------------------------------------
// K2: K,V projections of TAtt, written in MFMA fragment order (bf16).
//   Kf (B-frag for QK^T): per (b,h): [mt=16][lane=64][8]
//       lane l of frag mt holds K[mt*16 + (l&15)][(l>>4)*8 + j] * (1/sqrt(dh))
//   Vf (B-frag for PV):   per (b,h): [mc*2+dt =16][lane=64][8]
//       lane l holds V[mc*32 + (l>>4)*8 + j][dt*16 + (l&15)]
// ---------------------------------------------------------------------------
__global__ __launch_bounds__(256) void kv_kernel(const float* __restrict__ tatt,
                                                 const float* __restrict__ Wk,
                                                 const float* __restrict__ Wv,
                                                 short* __restrict__ Kf,
                                                 short* __restrict__ Vf) {
    __shared__ float trow[DD];
    int bid = blockIdx.x;       // b*N + n
    int b = bid >> 8;
    int n = bid & 255;
    int tid = threadIdx.x;      // output column c = h*32 + j
    trow[tid] = tatt[(size_t)bid * DD + tid];
    __syncthreads();
    const float4* wk4 = (const float4*)(Wk + (size_t)tid * DD);
    const float4* wv4 = (const float4*)(Wv + (size_t)tid * DD);
    const float4* t4 = (const float4*)trow;
    float accK = 0.f, accV = 0.f;
#pragma unroll 8
    for (int k = 0; k < DD / 4; ++k) {
        float4 tv = t4[k];
        float4 a = wk4[k];
        float4 v = wv4[k];
        accK += tv.x * a.x + tv.y * a.y + tv.z * a.z + tv.w * a.w;
        accV += tv.x * v.x + tv.y * v.y + tv.z * v.z + tv.w * v.w;
    }
    int h = tid >> 5, j = tid & 31;
    accK *= 0.17677669529663688f;   // fold 1/sqrt(32) into K

    int mt = n >> 4;
    int laneK = (n & 15) | ((j >> 3) << 4);
    int slotK = j & 7;
    Kf[((size_t)(b * HH + h) * 16 + mt) * 512 + laneK * 8 + slotK] = (short)f2bfu(accK);

    int mc = n >> 5;
    int grp = (n >> 3) & 3;
    int slotV = n & 7;
    int dt = j >> 4;
    int laneV = (j & 15) | (grp << 4);
    Vf[((size_t)(b * HH + h) * 16 + mc * 2 + dt) * 512 + laneV * 8 + slotV] = (short)f2bfu(accV);
}

// ---------------------------------------------------------------------------
// K3: Q = X @ W_Q^T via MFMA.  64x64 output tile per block (4 waves).
// X staged fp32->bf16 in LDS (full K=256); W frags converted in-register.
// Output Q bf16 in [B][T][H][N][32].
// ---------------------------------------------------------------------------
__global__ __launch_bounds__(256) void qproj_kernel(const float* __restrict__ x,
                                                    const float* __restrict__ Wq,
                                                    short* __restrict__ Qb) {
    __shared__ short Xb[64][264];   // pad 8 shorts: 16B-aligned rows, spread banks
    int bid = blockIdx.x;
    int ct = bid & 3;
    int rt = bid >> 2;
    int row0 = rt * 64, col0 = ct * 64;
    int tid = threadIdx.x;

    // stage X tile: 64 rows x 256 cols, fp32 -> bf16
#pragma unroll
    for (int i = 0; i < 16; ++i) {
        int f = i * 256 + tid;
        int rr = f >> 6;           // 0..63
        int c4 = f & 63;           // float4 index 0..63
        float4 xv = *(const float4*)(x + (size_t)(row0 + rr) * DD + c4 * 4);
        short4 sv;
        sv.x = (short)f2bfu(xv.x);
        sv.y = (short)f2bfu(xv.y);
        sv.z = (short)f2bfu(xv.z);
        sv.w = (short)f2bfu(xv.w);
        *(short4*)&Xb[rr][c4 * 4] = sv;
    }
    __syncthreads();

    int w = tid >> 6, l = tid & 63;
    int lg = l >> 4, lr = l & 15;
    int c = col0 + w * 16 + lr;     // this lane's output column (B-frag col)

    short8v bf[8];
#pragma unroll
    for (int kc = 0; kc < 8; ++kc) {
        const float* wp = Wq + (size_t)c * DD + kc * 32 + lg * 8;
        float4 w0 = *(const float4*)wp;
        float4 w1 = *(const float4*)(wp + 4);
        short8v tv;
        tv[0] = (short)f2bfu(w0.x); tv[1] = (short)f2bfu(w0.y);
        tv[2] = (short)f2bfu(w0.z); tv[3] = (short)f2bfu(w0.w);
        tv[4] = (short)f2bfu(w1.x); tv[5] = (short)f2bfu(w1.y);
        tv[6] = (short)f2bfu(w1.z); tv[7] = (short)f2bfu(w1.w);
        bf[kc] = tv;
    }

    f32x4 acc[4];
#pragma unroll
    for (int i = 0; i < 4; ++i) acc[i] = (f32x4){0.f, 0.f, 0.f, 0.f};

#pragma unroll
    for (int rt4 = 0; rt4 < 4; ++rt4) {
#pragma unroll
        for (int kc = 0; kc < 8; ++kc) {
            short8v a = *(const short8v*)&Xb[rt4 * 16 + lr][kc * 32 + lg * 8];
            acc[rt4] = __builtin_amdgcn_mfma_f32_16x16x32_bf16(a, bf[kc], acc[rt4], 0, 0, 0);
        }
    }

    int h = c >> 5, jj = c & 31;
#pragma unroll
    for (int rt4 = 0; rt4 < 4; ++rt4) {
#pragma unroll
        for (int r = 0; r < 4; ++r) {
            int row = row0 + rt4 * 16 + lg * 4 + r;
            int b = row >> 13;
            int t = (row >> 8) & 31;
            int n = row & 255;
            Qb[((((size_t)b * TT + t) * HH + h) * NN + n) * DH + jj] = (short)f2bfu(acc[rt4][r]);
        }
    }
}

// ---------------------------------------------------------------------------
// K4: per (b,t,h): S = Qh Kh^T (scale pre-folded); P = relu(S) + I; O = P Vh
// 4 waves/block; wave w owns q-rows w*64..w*64+63. K/V frags in registers.
// P repacked bf16 through LDS pair-layout [8 qpair][260] u32 per wave.
// ---------------------------------------------------------------------------
__global__ __launch_bounds__(256) void attn_kernel(const short* __restrict__ Qb,
                                                   const short* __restrict__ Kf,
                                                   const short* __restrict__ Vf,
                                                   float* __restrict__ out) {
    __shared__ unsigned int Plds[4][8][260];
    int bid = blockIdx.x;          // b*T*H + t*H + h
    int h = bid & 7;
    int t = (bid >> 3) & 31;
    int b = bid >> 8;
    int tid = threadIdx.x;
    int w = tid >> 6, l = tid & 63;
    int lg = l >> 4, lr = l & 15;

    const short* kbase = Kf + (size_t)(b * HH + h) * 16 * 512 + l * 8;
    const short* vbase = Vf + (size_t)(b * HH + h) * 16 * 512 + l * 8;
    short8v kfr[16], vfr[16];
#pragma unroll
    for (int i = 0; i < 16; ++i) {
        kfr[i] = *(const short8v*)(kbase + i * 512);
        vfr[i] = *(const short8v*)(vbase + i * 512);
    }

    const short* qbase = Qb + (((size_t)(b * TT + t) * HH + h) * NN + w * 64) * DH;
    const f32x4 zero = {0.f, 0.f, 0.f, 0.f};
    unsigned int (*P)[260] = Plds[w];
    unsigned int sel = (l & 1) ? 0x07060302u : 0x05040100u;  // v_perm selector
    int qp = lr >> 1;

    for (int qt = 0; qt < 4; ++qt) {
        short8v qf = *(const short8v*)(qbase + (qt * 16 + lr) * DH + lg * 8);
        int qb2 = w * 4 + qt;       // 16-block index of this wave's q-tile

        // ---- QK^T, relu, +identity, pack to bf16 pairs in LDS ----
#pragma unroll
        for (int mt = 0; mt < 16; ++mt) {
            f32x4 s = __builtin_amdgcn_mfma_f32_16x16x32_bf16(qf, kfr[mt], zero, 0, 0, 0);
            float p0 = fmaxf(s[0], 0.f);
            float p1 = fmaxf(s[1], 0.f);
            float p2 = fmaxf(s[2], 0.f);
            float p3 = fmaxf(s[3], 0.f);
            if (mt == qb2) {        // identity: +1 on the diagonal of P
                if (lr == lg * 4 + 0) p0 += 1.f;
                if (lr == lg * 4 + 1) p1 += 1.f;
                if (lr == lg * 4 + 2) p2 += 1.f;
                if (lr == lg * 4 + 3) p3 += 1.f;
            }
            P[2 * lg + 0][mt * 16 + lr] = pkbf(p0, p1);
            P[2 * lg + 1][mt * 16 + lr] = pkbf(p2, p3);
        }

        // ---- PV: read A-frags from LDS (pair layout), 2 MFMAs per m-chunk ----
        f32x4 o0 = zero, o1 = zero;
#pragma unroll
        for (int mc = 0; mc < 8; ++mc) {
            const unsigned int* pp = &P[qp][mc * 32 + lg * 8];
            u32x4 ra = *(const u32x4*)pp;
            u32x4 rb = *(const u32x4*)(pp + 4);
            union { unsigned int u[4]; short8v s; } pu;
            pu.u[0] = __builtin_amdgcn_perm(ra[1], ra[0], sel);
            pu.u[1] = __builtin_amdgcn_perm(ra[3], ra[2], sel);
            pu.u[2] = __builtin_amdgcn_perm(rb[1], rb[0], sel);
            pu.u[3] = __builtin_amdgcn_perm(rb[3], rb[2], sel);
            short8v pa = pu.s;
            o0 = __builtin_amdgcn_mfma_f32_16x16x32_bf16(pa, vfr[mc * 2 + 0], o0, 0, 0, 0);
            o1 = __builtin_amdgcn_mfma_f32_16x16x32_bf16(pa, vfr[mc * 2 + 1], o1, 0, 0, 0);
        }

        // ---- store fp32 output ----
#pragma unroll
        for (int r = 0; r < 4; ++r) {
            int n = w * 64 + qt * 16 + lg * 4 + r;
            float* op = out + ((size_t)(b * TT + t) * NN + n) * DD + h * DH + lr;
            op[0] = o0[r];
            op[16] = o1[r];
        }
    }
}

// ---------------------------------------------------------------------------
extern "C" void kernel_launch(void* const* d_in, const int* in_sizes, int n_in,
                              void* d_out, int out_size, void* d_ws, size_t ws_size,
                              hipStream_t stream) {
    (void)in_sizes; (void)n_in; (void)out_size; (void)ws_size;
    const float* x  = (const float*)d_in[0];
    // d_in[1] = boxes_in_flat: unused by the reference forward.
    const float* Wq = (const float*)d_in[2];
    const float* Wk = (const float*)d_in[3];
    const float* Wv = (const float*)d_in[4];
    float* out = (float*)d_out;

    // ws layout (bytes): tatt f32 [2MB] | Kf bf16 [1MB] | Vf bf16 [1MB] | Qb bf16 [32MB]
    char* base = (char*)d_ws;
    float* tatt = (float*)base;
    short* Kfp = (short*)(base + (size_t)2 * 1024 * 1024);
    short* Vfp = (short*)(base + (size_t)3 * 1024 * 1024);
    short* Qbp = (short*)(base + (size_t)4 * 1024 * 1024);

    tatt_kernel<<<(BB * NN * DD) / 256, 256, 0, stream>>>(x, tatt);
    kv_kernel<<<BB * NN, 256, 0, stream>>>(tatt, Wk, Wv, Kfp, Vfp);
    qproj_kernel<<<(BB * TT * NN / 64) * (DD / 64), 256, 0, stream>>>(x, Wq, Qbp);
    attn_kernel<<<BB * TT * HH, 256, 0, stream>>>(Qbp, Kfp, Vfp, out);
}

// Round 3
// 172.808 us; speedup vs baseline: 4.0591x; 2.0876x over previous
//
#include <hip/hip_runtime.h>
#include <hip/hip_bf16.h>

#define BB 8
#define TT 32
#define NN 256
#define DD 256
#define HH 8
#define DH 32

typedef __attribute__((ext_vector_type(8))) short short8v;   // 8 bf16 = 4 VGPR
typedef __attribute__((ext_vector_type(4))) float f32x4;
typedef __attribute__((ext_vector_type(4))) unsigned int u32x4;

static __device__ __forceinline__ unsigned short f2bfu(float f) {
    __hip_bfloat16 h = __float2bfloat16(f);
    unsigned short u;
    __builtin_memcpy(&u, &h, 2);
    return u;
}
static __device__ __forceinline__ unsigned int pkbf(float a, float b) {
    float2 f2; f2.x = a; f2.y = b;
    __hip_bfloat162 h2 = __float22bfloat162_rn(f2);
    unsigned int u;
    __builtin_memcpy(&u, &h2, 4);
    return u;
}

// ---------------------------------------------------------------------------
// K0: pre-fragment W matrices into MFMA B-frag order (bf16).
//   Wf[mat][ctile(16)][kc(8)][lane(64)][8]: lane l = (c&15)|(kg<<4) holds
//   W[ctile*16 + (l&15)][kc*32 + (l>>4)*8 + j]
// ---------------------------------------------------------------------------
__global__ __launch_bounds__(256) void wfrag_kernel(const float* __restrict__ Wq,
                                                    const float* __restrict__ Wk,
                                                    const float* __restrict__ Wv,
                                                    short* __restrict__ Wf) {
    int bid = blockIdx.x;          // mat*16 + ctile
    int mat = bid >> 4, ctile = bid & 15;
    const float* W = (mat == 0) ? Wq : (mat == 1) ? Wk : Wv;
    short* out = Wf + (size_t)mat * (16 * 8 * 64 * 8) + (size_t)ctile * (8 * 64 * 8);
    int tid = threadIdx.x;         // = k
    int kc = tid >> 5, kg = (tid >> 3) & 3, j = tid & 7;
#pragma unroll
    for (int i = 0; i < 16; ++i) { // i = local col
        float v = W[(size_t)(ctile * 16 + i) * DD + tid];
        int lane = i | (kg << 4);
        out[((size_t)kc * 64 + lane) * 8 + j] = (short)f2bfu(v);
    }
}

// ---------------------------------------------------------------------------
// K1: TAtt[b,n,d] = sum_t x[b,t,n,d] * softmax_t(x[b,:,n,d])
// ---------------------------------------------------------------------------
__global__ __launch_bounds__(256) void tatt_kernel(const float* __restrict__ x,
                                                   float* __restrict__ tatt) {
    int gid = blockIdx.x * 256 + threadIdx.x;      // over B*N*D = 524288
    int b = gid >> 16;
    int rem = gid & 0xFFFF;
    const float* xp = x + (size_t)b * TT * NN * DD + rem;
    float vals[TT];
    float mx = -3.0e38f;
#pragma unroll
    for (int t = 0; t < TT; ++t) {
        vals[t] = xp[(size_t)t * (NN * DD)];
        mx = fmaxf(mx, vals[t]);
    }
    float se = 0.f, wsum = 0.f;
#pragma unroll
    for (int t = 0; t < TT; ++t) {
        float e = __expf(vals[t] - mx);
        se += e;
        wsum += e * vals[t];
    }
    tatt[gid] = wsum / se;
}

// ---------------------------------------------------------------------------
// K2: K,V = TAtt @ {Wk,Wv}^T via MFMA, using pre-fragmented W.
// 32 blocks x 64 rows; outputs scattered to Kf/Vf fragment layouts
// (same layouts as round 2, verified):
//   Kf: [(b*H+h)*16 + n>>4][lane=(n&15)|((j>>3)<<4)][j&7], scale folded
//   Vf: [(b*H+h)*16 + (n>>5)*2+dt][lane=(j&15)|(((n>>3)&3)<<4)][n&7]
// ---------------------------------------------------------------------------
__global__ __launch_bounds__(256) void kv_kernel(const float* __restrict__ tatt,
                                                 const short* __restrict__ Wkf,
                                                 const short* __restrict__ Wvf,
                                                 short* __restrict__ Kf,
                                                 short* __restrict__ Vf) {
    __shared__ short Xb[64][264];
    int row0 = blockIdx.x * 64;    // rows over B*N = 2048
    int tid = threadIdx.x;

#pragma unroll
    for (int i = 0; i < 16; ++i) {
        int f = i * 256 + tid;
        int rr = f >> 6;
        int c4 = f & 63;
        float4 xv = *(const float4*)(tatt + (size_t)(row0 + rr) * DD + c4 * 4);
        short4 sv;
        sv.x = (short)f2bfu(xv.x);
        sv.y = (short)f2bfu(xv.y);
        sv.z = (short)f2bfu(xv.z);
        sv.w = (short)f2bfu(xv.w);
        *(short4*)&Xb[rr][c4 * 4] = sv;
    }
    __syncthreads();

    int w = tid >> 6, l = tid & 63;
    int lg = l >> 4, lr = l & 15;
    const f32x4 zero = {0.f, 0.f, 0.f, 0.f};

#pragma unroll
    for (int mat = 0; mat < 2; ++mat) {
        const short* Wfm = mat ? Wvf : Wkf;
#pragma unroll
        for (int ct = 0; ct < 4; ++ct) {
            int c = ct * 64 + w * 16 + lr;
            int ctile = ct * 4 + w;
            short8v bf[8];
#pragma unroll
            for (int kc = 0; kc < 8; ++kc)
                bf[kc] = *(const short8v*)(Wfm + (((size_t)ctile * 8 + kc) * 64 + l) * 8);
            int h = c >> 5, j = c & 31;
#pragma unroll
            for (int rt4 = 0; rt4 < 4; ++rt4) {
                f32x4 acc = zero;
#pragma unroll
                for (int kc = 0; kc < 8; ++kc) {
                    short8v a = *(const short8v*)&Xb[rt4 * 16 + lr][kc * 32 + lg * 8];
                    acc = __builtin_amdgcn_mfma_f32_16x16x32_bf16(a, bf[kc], acc, 0, 0, 0);
                }
#pragma unroll
                for (int r = 0; r < 4; ++r) {
                    int row = row0 + rt4 * 16 + lg * 4 + r;
                    int b = row >> 8, n = row & 255;
                    if (mat == 0) {
                        float val = acc[r] * 0.17677669529663688f;  // fold 1/sqrt(32)
                        int mt = n >> 4;
                        int laneK = (n & 15) | ((j >> 3) << 4);
                        Kf[((size_t)(b * HH + h) * 16 + mt) * 512 + laneK * 8 + (j & 7)] =
                            (short)f2bfu(val);
                    } else {
                        int mc = n >> 5, grp = (n >> 3) & 3, dt = j >> 4;
                        int laneV = (j & 15) | (grp << 4);
                        Vf[((size_t)(b * HH + h) * 16 + mc * 2 + dt) * 512 + laneV * 8 + (n & 7)] =
                            (short)f2bfu(acc[r]);
                    }
                }
            }
        }
    }
}

// ---------------------------------------------------------------------------
// K3: Q = X @ W_Q^T via MFMA; one block per 64-row tile computes all 256 cols.
// X staged once (bf16 LDS); W frags from pre-fragmented layout (coalesced).
// Output Q bf16 in [B][T][H][N][32].
// ---------------------------------------------------------------------------
__global__ __launch_bounds__(256) void qproj_kernel(const float* __restrict__ x,
                                                    const short* __restrict__ Wqf,
                                                    short* __restrict__ Qb) {
    __shared__ short Xb[64][264];
    int row0 = blockIdx.x * 64;    // rows over B*T*N = 65536
    int tid = threadIdx.x;

#pragma unroll
    for (int i = 0; i < 16; ++i) {
        int f = i * 256 + tid;
        int rr = f >> 6;
        int c4 = f & 63;
        float4 xv = *(const float4*)(x + (size_t)(row0 + rr) * DD + c4 * 4);
        short4 sv;
        sv.x = (short)f2bfu(xv.x);
        sv.y = (short)f2bfu(xv.y);
        sv.z = (short)f2bfu(xv.z);
        sv.w = (short)f2bfu(xv.w);
        *(short4*)&Xb[rr][c4 * 4] = sv;
    }
    __syncthreads();

    int w = tid >> 6, l = tid & 63;
    int lg = l >> 4, lr = l & 15;
    const f32x4 zero = {0.f, 0.f, 0.f, 0.f};

#pragma unroll
    for (int ct = 0; ct < 4; ++ct) {
        int c = ct * 64 + w * 16 + lr;
        int ctile = ct * 4 + w;
        short8v bf[8];
#pragma unroll
        for (int kc = 0; kc < 8; ++kc)
            bf[kc] = *(const short8v*)(Wqf + (((size_t)ctile * 8 + kc) * 64 + l) * 8);
        int h = c >> 5, jj = c & 31;
#pragma unroll
        for (int rt4 = 0; rt4 < 4; ++rt4) {
            f32x4 acc = zero;
#pragma unroll
            for (int kc = 0; kc < 8; ++kc) {
                short8v a = *(const short8v*)&Xb[rt4 * 16 + lr][kc * 32 + lg * 8];
                acc = __builtin_amdgcn_mfma_f32_16x16x32_bf16(a, bf[kc], acc, 0, 0, 0);
            }
#pragma unroll
            for (int r = 0; r < 4; ++r) {
                int row = row0 + rt4 * 16 + lg * 4 + r;
                int b = row >> 13;
                int t = (row >> 8) & 31;
                int n = row & 255;
                Qb[((((size_t)b * TT + t) * HH + h) * NN + n) * DH + jj] = (short)f2bfu(acc[r]);
            }
        }
    }
}

// ---------------------------------------------------------------------------
// K4: per (b,t,h): S = Qh Kh^T (scale pre-folded); P = relu(S) + I; O = P Vh
// (unchanged from round 2)
// ---------------------------------------------------------------------------
__global__ __launch_bounds__(256) void attn_kernel(const short* __restrict__ Qb,
                                                   const short* __restrict__ Kf,
                                                   const short* __restrict__ Vf,
                                                   float* __restrict__ out) {
    __shared__ unsigned int Plds[4][8][260];
    int bid = blockIdx.x;          // b*T*H + t*H + h
    int h = bid & 7;
    int t = (bid >> 3) & 31;
    int b = bid >> 8;
    int tid = threadIdx.x;
    int w = tid >> 6, l = tid & 63;
    int lg = l >> 4, lr = l & 15;

    const short* kbase = Kf + (size_t)(b * HH + h) * 16 * 512 + l * 8;
    const short* vbase = Vf + (size_t)(b * HH + h) * 16 * 512 + l * 8;
    short8v kfr[16], vfr[16];
#pragma unroll
    for (int i = 0; i < 16; ++i) {
        kfr[i] = *(const short8v*)(kbase + i * 512);
        vfr[i] = *(const short8v*)(vbase + i * 512);
    }

    const short* qbase = Qb + (((size_t)(b * TT + t) * HH + h) * NN + w * 64) * DH;
    const f32x4 zero = {0.f, 0.f, 0.f, 0.f};
    unsigned int (*P)[260] = Plds[w];
    unsigned int sel = (l & 1) ? 0x07060302u : 0x05040100u;  // v_perm selector
    int qp = lr >> 1;

    for (int qt = 0; qt < 4; ++qt) {
        short8v qf = *(const short8v*)(qbase + (qt * 16 + lr) * DH + lg * 8);
        int qb2 = w * 4 + qt;

        // ---- QK^T, relu, +identity, pack to bf16 pairs in LDS ----
#pragma unroll
        for (int mt = 0; mt < 16; ++mt) {
            f32x4 s = __builtin_amdgcn_mfma_f32_16x16x32_bf16(qf, kfr[mt], zero, 0, 0, 0);
            float p0 = fmaxf(s[0], 0.f);
            float p1 = fmaxf(s[1], 0.f);
            float p2 = fmaxf(s[2], 0.f);
            float p3 = fmaxf(s[3], 0.f);
            if (mt == qb2) {
                if (lr == lg * 4 + 0) p0 += 1.f;
                if (lr == lg * 4 + 1) p1 += 1.f;
                if (lr == lg * 4 + 2) p2 += 1.f;
                if (lr == lg * 4 + 3) p3 += 1.f;
            }
            P[2 * lg + 0][mt * 16 + lr] = pkbf(p0, p1);
            P[2 * lg + 1][mt * 16 + lr] = pkbf(p2, p3);
        }

        // ---- PV ----
        f32x4 o0 = zero, o1 = zero;
#pragma unroll
        for (int mc = 0; mc < 8; ++mc) {
            const unsigned int* pp = &P[qp][mc * 32 + lg * 8];
            u32x4 ra = *(const u32x4*)pp;
            u32x4 rb = *(const u32x4*)(pp + 4);
            union { unsigned int u[4]; short8v s; } pu;
            pu.u[0] = __builtin_amdgcn_perm(ra[1], ra[0], sel);
            pu.u[1] = __builtin_amdgcn_perm(ra[3], ra[2], sel);
            pu.u[2] = __builtin_amdgcn_perm(rb[1], rb[0], sel);
            pu.u[3] = __builtin_amdgcn_perm(rb[3], rb[2], sel);
            short8v pa = pu.s;
            o0 = __builtin_amdgcn_mfma_f32_16x16x32_bf16(pa, vfr[mc * 2 + 0], o0, 0, 0, 0);
            o1 = __builtin_amdgcn_mfma_f32_16x16x32_bf16(pa, vfr[mc * 2 + 1], o1, 0, 0, 0);
        }

        // ---- store fp32 output ----
#pragma unroll
        for (int r = 0; r < 4; ++r) {
            int n = w * 64 + qt * 16 + lg * 4 + r;
            float* op = out + ((size_t)(b * TT + t) * NN + n) * DD + h * DH + lr;
            op[0] = o0[r];
            op[16] = o1[r];
        }
    }
}

// ---------------------------------------------------------------------------
extern "C" void kernel_launch(void* const* d_in, const int* in_sizes, int n_in,
                              void* d_out, int out_size, void* d_ws, size_t ws_size,
                              hipStream_t stream) {
    (void)in_sizes; (void)n_in; (void)out_size; (void)ws_size;
    const float* x  = (const float*)d_in[0];
    // d_in[1] = boxes_in_flat: unused by the reference forward.
    const float* Wq = (const float*)d_in[2];
    const float* Wk = (const float*)d_in[3];
    const float* Wv = (const float*)d_in[4];
    float* out = (float*)d_out;

    // ws (bytes): tatt f32 [2MB] | Kf [1MB] | Vf [1MB] | Qb [32MB] | Wf [384KB]
    char* base = (char*)d_ws;
    float* tatt = (float*)base;
    short* Kfp = (short*)(base + (size_t)2 * 1024 * 1024);
    short* Vfp = (short*)(base + (size_t)3 * 1024 * 1024);
    short* Qbp = (short*)(base + (size_t)4 * 1024 * 1024);
    short* Wf  = (short*)(base + (size_t)36 * 1024 * 1024);
    short* Wqf = Wf;
    short* Wkf = Wf + (size_t)16 * 8 * 64 * 8;
    short* Wvf = Wkf + (size_t)16 * 8 * 64 * 8;

    wfrag_kernel<<<48, 256, 0, stream>>>(Wq, Wk, Wv, Wf);
    tatt_kernel<<<(BB * NN * DD) / 256, 256, 0, stream>>>(x, tatt);
    kv_kernel<<<BB * NN / 64, 256, 0, stream>>>(tatt, Wkf, Wvf, Kfp, Vfp);
    qproj_kernel<<<BB * TT * NN / 64, 256, 0, stream>>>(x, Wqf, Qbp);
    attn_kernel<<<BB * TT * HH, 256, 0, stream>>>(Qbp, Kfp, Vfp, out);
}